// Round 9
// baseline (415.972 us; speedup 1.0000x reference)
//
#include <hip/hip_runtime.h>
#include <hip/hip_bf16.h>
#include <math.h>

typedef __attribute__((ext_vector_type(8))) _Float16 f16x8;
typedef __attribute__((ext_vector_type(4))) float f32x4;

static __device__ __forceinline__ float sigmoidf_(float x) {
    return 1.0f / (1.0f + expf(-x));
}

#define GLL(src, dst) __builtin_amdgcn_global_load_lds(                         \
        (const __attribute__((address_space(1))) void*)(src),                   \
        (__attribute__((address_space(3))) void*)(dst), 16, 0, 0)

// ---------------------------------------------------------------------------
// fp32 -> fp16 with chunk-XOR pre-swizzle, 3 tensors in one launch.
// Logical chunk src[row][kc] lands at dst[row][kcs], kcs=(kc&~7)|((kc&7)^(row&7)).
// GEMMs stage LDS linearly (global_load_lds); ds_read applies the same XOR
// -> conflict-free b128 fragment reads (verified: SQ_LDS_BANK_CONFLICT = 0).
// ---------------------------------------------------------------------------
__global__ void cvt_all(const float* __restrict__ s0, _Float16* __restrict__ d0, int n0,
                        const float* __restrict__ s1, _Float16* __restrict__ d1, int n1,
                        const float* __restrict__ s2, _Float16* __restrict__ d2, int n2,
                        int ck01, int ck2)
{
    int c = blockIdx.x * 256 + threadIdx.x;
    const float* s; _Float16* d; int ck;
    if (c < n0)            { s = s0; d = d0; ck = ck01; }
    else if (c < n0 + n1)  { c -= n0; s = s1; d = d1; ck = ck01; }
    else                   { c -= n0 + n1; if (c >= n2) return; s = s2; d = d2; ck = ck2; }
    const int row = c / ck;
    const int kc  = c - row * ck;
    const int kcs = (kc & ~7) | ((kc & 7) ^ (row & 7));
    const float* sp = s + (size_t)c * 8;
    float4 v0 = *(const float4*)sp;
    float4 v1 = *(const float4*)(sp + 4);
    f16x8 h;
    h[0] = (_Float16)v0.x; h[1] = (_Float16)v0.y;
    h[2] = (_Float16)v0.z; h[3] = (_Float16)v0.w;
    h[4] = (_Float16)v1.x; h[5] = (_Float16)v1.y;
    h[6] = (_Float16)v1.z; h[7] = (_Float16)v1.w;
    *(f16x8*)(d + (size_t)row * ((size_t)ck * 8) + (size_t)kcs * 8) = h;
}

// ---------------------------------------------------------------------------
// GEMM1 + GRU gate, fused. Block tile: 128 batch-rows x 32 h-columns, but the
// B-operand gathers 96 w_ih rows {h0..h0+31, H+h0.., 2H+h0..} so each block
// owns all three gate slices for its h-range. 4 waves split batch 4x1
// (WM=32, WN=96). 2-phase prefetch: stage(t+1) || compute(t), 1 barrier/step.
// Epilogue: r/z/n from fp32 accumulators -> h_new, written fp16 XOR-swizzled.
// ---------------------------------------------------------------------------
__launch_bounds__(256, 2)
__global__ void gemm1_gate(const _Float16* __restrict__ A,   // x16 [B][I] swz
                           const _Float16* __restrict__ W,   // wih16 [3H][I] swz
                           const float* __restrict__ b_ih,
                           const float* __restrict__ b_hh,
                           _Float16* __restrict__ hn,        // [B][H] swz
                           int H, int I)
{
    constexpr int BM = 128, BNH = 32, BN = 96, BK = 64;
    constexpr int MR = 2, NR = 6;            // per-wave 32x96 in 16x16 frags

    __shared__ _Float16 As[2][BM * BK];
    __shared__ _Float16 Bs[2][BN * BK];

    const int tid  = threadIdx.x;
    const int lane = tid & 63;
    const int wid  = tid >> 6;               // 0..3 -> batch quadrant
    const int lr   = lane & 15;
    const int kb   = lane >> 4;
    const int brow = blockIdx.y * BM;
    const int h0   = blockIdx.x * BNH;

    // staging sources (per thread): A 4 chunks, B 3 chunks
    const _Float16* asrc[4];
#pragma unroll
    for (int i = 0; i < 4; ++i) {
        const int c = i * 256 + tid;
        asrc[i] = A + (size_t)(brow + (c >> 3)) * I + (c & 7) * 8;
    }
    const _Float16* bsrc[3];
#pragma unroll
    for (int i = 0; i < 3; ++i) {
        const int c = i * 256 + tid;
        const int r = c >> 3, grp = r >> 5, hr = r & 31;
        bsrc[i] = W + (size_t)(grp * H + h0 + hr) * I + (c & 7) * 8;
    }

    f32x4 acc[MR][NR] = {};

    auto stage = [&](int buf, int kt) {
#pragma unroll
        for (int i = 0; i < 4; ++i)
            GLL(asrc[i] + (size_t)kt * BK, &As[buf][(i * 256 + tid) * 8]);
#pragma unroll
        for (int i = 0; i < 3; ++i)
            GLL(bsrc[i] + (size_t)kt * BK, &Bs[buf][(i * 256 + tid) * 8]);
    };
    auto compute = [&](int buf) {
#pragma unroll
        for (int ks = 0; ks < 2; ++ks) {
            f16x8 af[MR], bf[NR];
#pragma unroll
            for (int m = 0; m < MR; ++m) {
                const int row = wid * 32 + m * 16 + lr;
                af[m] = *(const f16x8*)&As[buf][row * BK + ((ks * 4 + kb) ^ (row & 7)) * 8];
            }
#pragma unroll
            for (int n = 0; n < NR; ++n) {
                const int row = n * 16 + lr;
                bf[n] = *(const f16x8*)&Bs[buf][row * BK + ((ks * 4 + kb) ^ (row & 7)) * 8];
            }
#pragma unroll
            for (int n = 0; n < NR; ++n)
#pragma unroll
                for (int m = 0; m < MR; ++m)
                    acc[m][n] = __builtin_amdgcn_mfma_f32_16x16x32_f16(af[m], bf[n], acc[m][n], 0, 0, 0);
        }
    };

    const int nt = I / BK;
    stage(0, 0);
    __syncthreads();
    int cur = 0;
    for (int t = 0; t < nt - 1; ++t) {
        stage(cur ^ 1, t + 1);       // prefetch overlaps compute; barrier drains it
        compute(cur);
        __syncthreads();
        cur ^= 1;
    }
    compute(cur);

    // epilogue: C col = lane&15, row = (lane>>4)*4 + j (HW-verified).
    // cols 0-31 -> i_r, 32-63 -> i_z, 64-95 -> i_n for h = h0 + col%32.
#pragma unroll
    for (int q = 0; q < 2; ++q) {
        const int h  = h0 + q * 16 + lr;
        const float br_ = b_ih[h]         + b_hh[h];
        const float bz_ = b_ih[H + h]     + b_hh[H + h];
        const float bn_ = b_ih[2 * H + h];
        const float hnb = b_hh[2 * H + h];
        const int hc  = h >> 3;
        const int hlo = h & 7;
#pragma unroll
        for (int m = 0; m < MR; ++m) {
            const int r0 = brow + wid * 32 + m * 16 + kb * 4;
#pragma unroll
            for (int j = 0; j < 4; ++j) {
                const int b = r0 + j;
                const float rr = sigmoidf_(acc[m][q][j]     + br_);
                const float zz = sigmoidf_(acc[m][q + 2][j] + bz_);
                const float hv = (1.0f - zz) * tanhf(acc[m][q + 4][j] + bn_ + rr * hnb);
                const int hcs = (hc & ~7) | ((hc & 7) ^ (b & 7));
                hn[(size_t)b * H + hcs * 8 + hlo] = (_Float16)hv;
            }
        }
    }
}

// ---------------------------------------------------------------------------
// GEMM2 + sigmoid + T-broadcast, fused. 64x64 (b,o) tile, 4 waves 2x2,
// 2-phase prefetch. Epilogue: sigmoid values -> LDS tile -> fully coalesced
// float2 stream-out of out[b][o0:o0+64][0:T] (64*T contiguous floats per b;
// T=30 -> exactly 15 float2 per o, no straddle).
// ---------------------------------------------------------------------------
__launch_bounds__(256, 2)
__global__ void gemm2_bcast(const _Float16* __restrict__ A,   // hn16 [B][H] swz
                            const _Float16* __restrict__ Bw,  // wcls16 [O][H] swz
                            const float* __restrict__ bias,
                            float* __restrict__ out,          // [B][O][T]
                            int O, int K, int T)
{
    constexpr int BT = 64, BK = 64;
    constexpr int MR = 2, NR = 2;            // per-wave 32x32

    __shared__ _Float16 As[2][BT * BK];
    __shared__ _Float16 Bs[2][BT * BK];
    __shared__ float resS[64][65];           // +1 pad: conflict-free writes

    const int tid  = threadIdx.x;
    const int lane = tid & 63;
    const int wid  = tid >> 6;
    const int wr   = wid >> 1;
    const int wc   = wid & 1;
    const int lr   = lane & 15;
    const int kb   = lane >> 4;
    const int brow = blockIdx.y * BT;
    const int bcol = blockIdx.x * BT;

    const _Float16* asrc[2];
    const _Float16* bsrc[2];
#pragma unroll
    for (int i = 0; i < 2; ++i) {
        const int c = i * 256 + tid;
        asrc[i] = A  + (size_t)(brow + (c >> 3)) * K + (c & 7) * 8;
        bsrc[i] = Bw + (size_t)(bcol + (c >> 3)) * K + (c & 7) * 8;
    }

    f32x4 acc[MR][NR] = {};

    auto stage = [&](int buf, int kt) {
#pragma unroll
        for (int i = 0; i < 2; ++i) {
            GLL(asrc[i] + (size_t)kt * BK, &As[buf][(i * 256 + tid) * 8]);
            GLL(bsrc[i] + (size_t)kt * BK, &Bs[buf][(i * 256 + tid) * 8]);
        }
    };
    auto compute = [&](int buf) {
#pragma unroll
        for (int ks = 0; ks < 2; ++ks) {
            f16x8 af[MR], bf[NR];
#pragma unroll
            for (int m = 0; m < MR; ++m) {
                const int row = wr * 32 + m * 16 + lr;
                af[m] = *(const f16x8*)&As[buf][row * BK + ((ks * 4 + kb) ^ (row & 7)) * 8];
            }
#pragma unroll
            for (int n = 0; n < NR; ++n) {
                const int row = wc * 32 + n * 16 + lr;
                bf[n] = *(const f16x8*)&Bs[buf][row * BK + ((ks * 4 + kb) ^ (row & 7)) * 8];
            }
#pragma unroll
            for (int n = 0; n < NR; ++n)
#pragma unroll
                for (int m = 0; m < MR; ++m)
                    acc[m][n] = __builtin_amdgcn_mfma_f32_16x16x32_f16(af[m], bf[n], acc[m][n], 0, 0, 0);
        }
    };

    const int nt = K / BK;
    stage(0, 0);
    __syncthreads();
    int cur = 0;
    for (int t = 0; t < nt - 1; ++t) {
        stage(cur ^ 1, t + 1);
        compute(cur);
        __syncthreads();
        cur ^= 1;
    }
    compute(cur);

    // sigmoid -> LDS tile
#pragma unroll
    for (int m = 0; m < MR; ++m) {
        const int rl = wr * 32 + m * 16 + kb * 4;
#pragma unroll
        for (int n = 0; n < NR; ++n) {
            const int cl = wc * 32 + n * 16 + lr;
            const float bv = bias[bcol + cl];
#pragma unroll
            for (int j = 0; j < 4; ++j)
                resS[rl + j][cl] = sigmoidf_(acc[m][n][j] + bv);
        }
    }
    __syncthreads();

    // stream-out: per b-row, 64*T contiguous floats
    if (!(T & 1)) {
        const int ppr = 32 * T;              // float2 per row (64*T/2)
        const int hT  = T >> 1;
        for (int j = tid; j < 64 * ppr; j += 256) {
            const int rl  = j / ppr;
            const int rem = j - rl * ppr;
            const int ol  = rem / hT;
            const float v = resS[rl][ol];
            float2* p = (float2*)out + ((size_t)(brow + rl) * O + bcol) * hT + rem;
            *p = make_float2(v, v);
        }
    } else {
        const int ppr = 64 * T;
        for (int j = tid; j < 64 * ppr; j += 256) {
            const int rl  = j / ppr;
            const int rem = j - rl * ppr;
            const int ol  = rem / T;
            out[((size_t)(brow + rl) * O + bcol) * T + rem] = resS[rl][ol];
        }
    }
}

extern "C" void kernel_launch(void* const* d_in, const int* in_sizes, int n_in,
                              void* d_out, int out_size, void* d_ws, size_t ws_size,
                              hipStream_t stream)
{
    const float* x     = (const float*)d_in[0];
    const float* w_ih  = (const float*)d_in[1];
    // d_in[2] = w_hh: dead (hidden state stays 0)
    const float* b_ih  = (const float*)d_in[3];
    const float* b_hh  = (const float*)d_in[4];
    const float* w_cls = (const float*)d_in[5];
    const float* b_cls = (const float*)d_in[6];

    const int H3 = in_sizes[3];          // 6144
    const int H  = H3 / 3;               // 2048
    const int I  = in_sizes[1] / H3;     // 2048
    const int B  = in_sizes[0] / I;      // 1024
    const int O  = in_sizes[6];          // 2048
    const int T  = out_size / (B * O);   // 30

    // ws (16.8 MB): x16 | wcls16 | hn16
    _Float16* x16    = (_Float16*)d_ws;                 // B*I fp16
    _Float16* wcls16 = x16 + (size_t)B * I;             // O*H fp16
    _Float16* hn16   = wcls16 + (size_t)O * H;          // B*H fp16

    // d_out doubles as scratch for wih16 (24 MB); gemm1 consumes it before
    // gemm2's epilogue overwrites the whole output buffer (stream-ordered).
    _Float16* wih16 = (_Float16*)d_out;

    dim3 blk(256);

    // fp32 -> fp16 pre-swizzled: x, w_ih, w_cls in one launch
    {
        const int n0 = B * I / 8, n1 = H3 * I / 8, n2 = O * H / 8;
        const int tot = n0 + n1 + n2;
        cvt_all<<<(tot + 255) / 256, blk, 0, stream>>>(x, x16, n0, w_ih, wih16, n1,
                                                       w_cls, wcls16, n2, I / 8, H / 8);
    }

    // GEMM1+gate: hn16 = GRU(x @ w_ih^T + b_ih, b_hh). Grid (64,8)=512 = 2/CU.
    gemm1_gate<<<dim3(H / 32, B / 128), blk, 0, stream>>>(
        x16, wih16, b_ih, b_hh, hn16, H, I);

    // GEMM2+sigmoid+broadcast: out = sigmoid(hn @ w_cls^T + b_cls) x T.
    // Grid (32,16)=512 = 2/CU; epilogue streams 252 MB coalesced.
    gemm2_bcast<<<dim3(O / 64, B / 64), blk, 0, stream>>>(
        hn16, wcls16, b_cls, (float*)d_out, O, H, T);
}

// Round 10
// 391.851 us; speedup vs baseline: 1.0616x; 1.0616x over previous
//
#include <hip/hip_runtime.h>
#include <hip/hip_bf16.h>
#include <math.h>

typedef __attribute__((ext_vector_type(8))) _Float16 f16x8;
typedef __attribute__((ext_vector_type(4))) float f32x4;

static __device__ __forceinline__ float sigmoidf_(float x) {
    return 1.0f / (1.0f + expf(-x));
}

#define GLL(src, dst) __builtin_amdgcn_global_load_lds(                         \
        (const __attribute__((address_space(1))) void*)(src),                   \
        (__attribute__((address_space(3))) void*)(dst), 16, 0, 0)

#define WAITVM(N) do { asm volatile("s_waitcnt vmcnt(%0)" :: "i"(N) : "memory"); \
                       __builtin_amdgcn_sched_barrier(0); } while (0)
#define BARRIER() do { __builtin_amdgcn_s_barrier();                             \
                       __builtin_amdgcn_sched_barrier(0); } while (0)

// ---------------------------------------------------------------------------
// fp32 -> fp16 with chunk-XOR pre-swizzle, 3 tensors in one launch.
// Logical chunk src[row][kc] lands at dst[row][kcs], kcs=(kc&~7)|((kc&7)^(row&7)).
// GEMMs stage LDS linearly (global_load_lds); ds_read applies the same XOR
// -> conflict-free b128 fragment reads (verified: SQ_LDS_BANK_CONFLICT = 0).
// ---------------------------------------------------------------------------
__global__ void cvt_all(const float* __restrict__ s0, _Float16* __restrict__ d0, int n0,
                        const float* __restrict__ s1, _Float16* __restrict__ d1, int n1,
                        const float* __restrict__ s2, _Float16* __restrict__ d2, int n2,
                        int ck01, int ck2)
{
    int c = blockIdx.x * 256 + threadIdx.x;
    const float* s; _Float16* d; int ck;
    if (c < n0)            { s = s0; d = d0; ck = ck01; }
    else if (c < n0 + n1)  { c -= n0; s = s1; d = d1; ck = ck01; }
    else                   { c -= n0 + n1; if (c >= n2) return; s = s2; d = d2; ck = ck2; }
    const int row = c / ck;
    const int kc  = c - row * ck;
    const int kcs = (kc & ~7) | ((kc & 7) ^ (row & 7));
    const float* sp = s + (size_t)c * 8;
    float4 v0 = *(const float4*)sp;
    float4 v1 = *(const float4*)(sp + 4);
    f16x8 h;
    h[0] = (_Float16)v0.x; h[1] = (_Float16)v0.y;
    h[2] = (_Float16)v0.z; h[3] = (_Float16)v0.w;
    h[4] = (_Float16)v1.x; h[5] = (_Float16)v1.y;
    h[6] = (_Float16)v1.z; h[7] = (_Float16)v1.w;
    *(f16x8*)(d + (size_t)row * ((size_t)ck * 8) + (size_t)kcs * 8) = h;
}

// ---------------------------------------------------------------------------
// GEMM1 + GRU gate, fused. 128 batch-rows x 32 h-cols per block; B-operand
// gathers 96 w_ih rows {r,z,n} for the h-range. 4 waves split batch.
// Counted-vmcnt 2-deep pipeline: 2 tiles in flight, vmcnt(7) per step (own
// loads/tile = 7), raw s_barrier, stage(t+2) after the read-done barrier.
// ---------------------------------------------------------------------------
__launch_bounds__(256, 2)
__global__ void gemm1_gate(const _Float16* __restrict__ A,   // x16 [B][I] swz
                           const _Float16* __restrict__ W,   // wih16 [3H][I] swz
                           const float* __restrict__ b_ih,
                           const float* __restrict__ b_hh,
                           _Float16* __restrict__ hn,        // [B][H] swz
                           int H, int I)
{
    constexpr int BM = 128, BNH = 32, BN = 96, BK = 64;
    constexpr int MR = 2, NR = 6;

    __shared__ _Float16 As[2][BM * BK];
    __shared__ _Float16 Bs[2][BN * BK];

    const int tid  = threadIdx.x;
    const int lane = tid & 63;
    const int wid  = tid >> 6;
    const int lr   = lane & 15;
    const int kb   = lane >> 4;
    const int brow = blockIdx.y * BM;
    const int h0   = blockIdx.x * BNH;

    const _Float16* asrc[4];
#pragma unroll
    for (int i = 0; i < 4; ++i) {
        const int c = i * 256 + tid;
        asrc[i] = A + (size_t)(brow + (c >> 3)) * I + (c & 7) * 8;
    }
    const _Float16* bsrc[3];
#pragma unroll
    for (int i = 0; i < 3; ++i) {
        const int c = i * 256 + tid;
        const int r = c >> 3, grp = r >> 5, hr = r & 31;
        bsrc[i] = W + (size_t)(grp * H + h0 + hr) * I + (c & 7) * 8;
    }

    f32x4 acc[MR][NR] = {};

    auto stage = [&](int buf, int kt) {
#pragma unroll
        for (int i = 0; i < 4; ++i)
            GLL(asrc[i] + (size_t)kt * BK, &As[buf][(i * 256 + tid) * 8]);
#pragma unroll
        for (int i = 0; i < 3; ++i)
            GLL(bsrc[i] + (size_t)kt * BK, &Bs[buf][(i * 256 + tid) * 8]);
    };
    auto compute = [&](int buf) {
#pragma unroll
        for (int ks = 0; ks < 2; ++ks) {
            f16x8 af[MR], bf[NR];
#pragma unroll
            for (int m = 0; m < MR; ++m) {
                const int row = wid * 32 + m * 16 + lr;
                af[m] = *(const f16x8*)&As[buf][row * BK + ((ks * 4 + kb) ^ (row & 7)) * 8];
            }
#pragma unroll
            for (int n = 0; n < NR; ++n) {
                const int row = n * 16 + lr;
                bf[n] = *(const f16x8*)&Bs[buf][row * BK + ((ks * 4 + kb) ^ (row & 7)) * 8];
            }
#pragma unroll
            for (int n = 0; n < NR; ++n)
#pragma unroll
                for (int m = 0; m < MR; ++m)
                    acc[m][n] = __builtin_amdgcn_mfma_f32_16x16x32_f16(af[m], bf[n], acc[m][n], 0, 0, 0);
        }
    };

    const int nt = I / BK;                 // >= 2
    stage(0, 0);
    stage(1, 1);                           // 14 loads in flight
    for (int t = 0; t < nt - 1; ++t) {
        WAITVM(7);                         // my tile-t loads done; t+1 in flight
        BARRIER();                         // everyone's tile-t loads done
        compute(t & 1);
        BARRIER();                         // all waves done reading buf[t&1]
        if (t + 2 < nt) stage(t & 1, t + 2);
    }
    WAITVM(0);
    BARRIER();
    compute((nt - 1) & 1);

    // epilogue: C col = lane&15, row = (lane>>4)*4 + j (HW-verified).
#pragma unroll
    for (int q = 0; q < 2; ++q) {
        const int h  = h0 + q * 16 + lr;
        const float br_ = b_ih[h]         + b_hh[h];
        const float bz_ = b_ih[H + h]     + b_hh[H + h];
        const float bn_ = b_ih[2 * H + h];
        const float hnb = b_hh[2 * H + h];
        const int hc  = h >> 3;
        const int hlo = h & 7;
#pragma unroll
        for (int m = 0; m < MR; ++m) {
            const int r0 = brow + wid * 32 + m * 16 + kb * 4;
#pragma unroll
            for (int j = 0; j < 4; ++j) {
                const int b = r0 + j;
                const float rr = sigmoidf_(acc[m][q][j]     + br_);
                const float zz = sigmoidf_(acc[m][q + 2][j] + bz_);
                const float hv = (1.0f - zz) * tanhf(acc[m][q + 4][j] + bn_ + rr * hnb);
                const int hcs = (hc & ~7) | ((hc & 7) ^ (b & 7));
                hn[(size_t)b * H + hcs * 8 + hlo] = (_Float16)hv;
            }
        }
    }
}

// ---------------------------------------------------------------------------
// GEMM2 + sigmoid + T-broadcast, fused. 64x64 (b,o) tile, 4 waves 2x2.
// Counted-vmcnt 2-deep pipeline (vmcnt(4)/step). resS is ALIASED into the
// As/Bs LDS block (live only after the K-loop) -> 32 KB total -> 2 blocks/CU
// for the 252 MB stream-out (round-9 had 81 KB -> 1 block/CU -> write-BW
// starved). TT>0: compile-time T (divisions become magic-muls).
// ---------------------------------------------------------------------------
template <int TT>
__launch_bounds__(256, 2)
__global__ void gemm2_bcast(const _Float16* __restrict__ A,   // hn16 [B][H] swz
                            const _Float16* __restrict__ Bw,  // wcls16 [O][H] swz
                            const float* __restrict__ bias,
                            float* __restrict__ out,          // [B][O][T]
                            int O, int K, int Tdyn)
{
    constexpr int BT = 64, BK = 64;
    constexpr int MR = 2, NR = 2;

    __shared__ __align__(16) char smem[2 * BT * BK * 2 * 2];   // 32 KB
    _Float16 (*As)[BT * BK] = (_Float16(*)[BT * BK])smem;
    _Float16 (*Bs)[BT * BK] = (_Float16(*)[BT * BK])(smem + 2 * BT * BK * 2);
    float (*resS)[65] = (float(*)[65])smem;                    // 16.6 KB alias

    const int tid  = threadIdx.x;
    const int lane = tid & 63;
    const int wid  = tid >> 6;
    const int wr   = wid >> 1;
    const int wc   = wid & 1;
    const int lr   = lane & 15;
    const int kb   = lane >> 4;
    const int brow = blockIdx.y * BT;
    const int bcol = blockIdx.x * BT;

    const _Float16* asrc[2];
    const _Float16* bsrc[2];
#pragma unroll
    for (int i = 0; i < 2; ++i) {
        const int c = i * 256 + tid;
        asrc[i] = A  + (size_t)(brow + (c >> 3)) * K + (c & 7) * 8;
        bsrc[i] = Bw + (size_t)(bcol + (c >> 3)) * K + (c & 7) * 8;
    }

    f32x4 acc[MR][NR] = {};

    auto stage = [&](int buf, int kt) {
#pragma unroll
        for (int i = 0; i < 2; ++i) {
            GLL(asrc[i] + (size_t)kt * BK, &As[buf][(i * 256 + tid) * 8]);
            GLL(bsrc[i] + (size_t)kt * BK, &Bs[buf][(i * 256 + tid) * 8]);
        }
    };
    auto compute = [&](int buf) {
#pragma unroll
        for (int ks = 0; ks < 2; ++ks) {
            f16x8 af[MR], bf[NR];
#pragma unroll
            for (int m = 0; m < MR; ++m) {
                const int row = wr * 32 + m * 16 + lr;
                af[m] = *(const f16x8*)&As[buf][row * BK + ((ks * 4 + kb) ^ (row & 7)) * 8];
            }
#pragma unroll
            for (int n = 0; n < NR; ++n) {
                const int row = wc * 32 + n * 16 + lr;
                bf[n] = *(const f16x8*)&Bs[buf][row * BK + ((ks * 4 + kb) ^ (row & 7)) * 8];
            }
#pragma unroll
            for (int n = 0; n < NR; ++n)
#pragma unroll
                for (int m = 0; m < MR; ++m)
                    acc[m][n] = __builtin_amdgcn_mfma_f32_16x16x32_f16(af[m], bf[n], acc[m][n], 0, 0, 0);
        }
    };

    const int nt = K / BK;                 // >= 2
    stage(0, 0);
    stage(1, 1);                           // 8 loads in flight
    for (int t = 0; t < nt - 1; ++t) {
        WAITVM(4);
        BARRIER();
        compute(t & 1);
        BARRIER();
        if (t + 2 < nt) stage(t & 1, t + 2);
    }
    WAITVM(0);
    BARRIER();
    compute((nt - 1) & 1);

    __syncthreads();                       // As/Bs reads done before resS alias reuse

    // sigmoid -> LDS tile
#pragma unroll
    for (int m = 0; m < MR; ++m) {
        const int rl = wr * 32 + m * 16 + kb * 4;
#pragma unroll
        for (int n = 0; n < NR; ++n) {
            const int cl = wc * 32 + n * 16 + lr;
            const float bv = bias[bcol + cl];
#pragma unroll
            for (int j = 0; j < 4; ++j)
                resS[rl + j][cl] = sigmoidf_(acc[m][n][j] + bv);
        }
    }
    __syncthreads();

    // stream-out: per b-row, 64*T contiguous floats, lane-adjacent
    const int T = (TT > 0) ? TT : Tdyn;
    if (!(T & 1)) {
        const int hT  = T >> 1;
        const int ppr = 32 * T;            // float2 per row
        for (int j = tid; j < 64 * ppr; j += 256) {
            const int rl  = j / ppr;
            const int rem = j - rl * ppr;
            const int ol  = rem / hT;
            const float v = resS[rl][ol];
            float2* p = (float2*)out + ((size_t)(brow + rl) * O + bcol) * hT + rem;
            *p = make_float2(v, v);
        }
    } else {
        const int ppr = 64 * T;
        for (int j = tid; j < 64 * ppr; j += 256) {
            const int rl  = j / ppr;
            const int rem = j - rl * ppr;
            const int ol  = rem / T;
            out[((size_t)(brow + rl) * O + bcol) * T + rem] = resS[rl][ol];
        }
    }
}

extern "C" void kernel_launch(void* const* d_in, const int* in_sizes, int n_in,
                              void* d_out, int out_size, void* d_ws, size_t ws_size,
                              hipStream_t stream)
{
    const float* x     = (const float*)d_in[0];
    const float* w_ih  = (const float*)d_in[1];
    // d_in[2] = w_hh: dead (hidden state stays 0)
    const float* b_ih  = (const float*)d_in[3];
    const float* b_hh  = (const float*)d_in[4];
    const float* w_cls = (const float*)d_in[5];
    const float* b_cls = (const float*)d_in[6];

    const int H3 = in_sizes[3];          // 6144
    const int H  = H3 / 3;               // 2048
    const int I  = in_sizes[1] / H3;     // 2048
    const int B  = in_sizes[0] / I;      // 1024
    const int O  = in_sizes[6];          // 2048
    const int T  = out_size / (B * O);   // 30

    // ws (16.8 MB): x16 | wcls16 | hn16
    _Float16* x16    = (_Float16*)d_ws;
    _Float16* wcls16 = x16 + (size_t)B * I;
    _Float16* hn16   = wcls16 + (size_t)O * H;

    // d_out doubles as scratch for wih16 (24 MB); fully consumed before
    // gemm2's epilogue overwrites the output buffer (stream-ordered).
    _Float16* wih16 = (_Float16*)d_out;

    dim3 blk(256);

    // fp32 -> fp16 pre-swizzled: x, w_ih, w_cls in one launch
    {
        const int n0 = B * I / 8, n1 = H3 * I / 8, n2 = O * H / 8;
        const int tot = n0 + n1 + n2;
        cvt_all<<<(tot + 255) / 256, blk, 0, stream>>>(x, x16, n0, w_ih, wih16, n1,
                                                       w_cls, wcls16, n2, I / 8, H / 8);
    }

    // GEMM1+gate: hn16 = GRU(x @ w_ih^T + b_ih, b_hh). Grid (64,8)=512 = 2/CU.
    gemm1_gate<<<dim3(H / 32, B / 128), blk, 0, stream>>>(
        x16, wih16, b_ih, b_hh, hn16, H, I);

    // GEMM2+sigmoid+broadcast. Grid (32,16)=512 = 2/CU, now truly 2/CU by LDS.
    if (T == 30)
        gemm2_bcast<30><<<dim3(O / 64, B / 64), blk, 0, stream>>>(
            hn16, wcls16, b_cls, (float*)d_out, O, H, T);
    else
        gemm2_bcast<0><<<dim3(O / 64, B / 64), blk, 0, stream>>>(
            hn16, wcls16, b_cls, (float*)d_out, O, H, T);
}